// Round 3
// baseline (603.716 us; speedup 1.0000x reference)
//
#include <hip/hip_runtime.h>

// FNOBlock on MI355X — zero-big-ws design.
//   d_out (134 MB, 33.5M floats) holds: packed bf16 complex planes (uint32) for the
//   intermediate IFFT stages, overwritten in-place by the final real fp32 output.
//   X = fft2(x)                          (tiny naive DFTs, fp32, ws smalls)
//   fused:  per 32 complex rows: A=phase*crelu(X*w0) on the fly -> GEMM1(crelu,b1)
//           -> GEMM2(b2) -> v-axis IFFT in LDS -> packed bf16 planes in d_out
//   fft_m:  m-axis IFFT, in-place on packed planes
//   fft_b:  b-axis IFFT, in-place, writes REAL fp32 output over its own slots

typedef unsigned short ushort_t;
typedef unsigned int   uint_t;
typedef __attribute__((ext_vector_type(8))) short short8b;   // 8 x bf16
typedef __attribute__((ext_vector_type(4))) float f32x4;

__device__ __forceinline__ ushort_t f2bf(float f){
  union { float f; uint_t u; } v; v.f = f;
  uint_t r = v.u + 0x7FFFu + ((v.u >> 16) & 1u);   // RNE
  return (ushort_t)(r >> 16);
}
__device__ __forceinline__ uint_t pack_bf(float re, float im){
  return (uint_t)f2bf(re) | ((uint_t)f2bf(im) << 16);
}
__device__ __forceinline__ float bf_lo(uint_t u){
  union { uint_t u; float f; } v; v.u = u << 16; return v.f;
}
__device__ __forceinline__ float bf_hi(uint_t u){
  union { uint_t u; float f; } v; v.u = u & 0xFFFF0000u; return v.f;
}
__device__ __forceinline__ void gld16(const void* g, void* l){
  __builtin_amdgcn_global_load_lds(
      (const __attribute__((address_space(1))) void*)g,
      (__attribute__((address_space(3))) void*)l, 16, 0, 0);
}

// ---------------- tables ----------------
__global__ void fill_tables(float2* t256f, float2* t256i, float2* t512f, float2* t512i){
  int i = threadIdx.x;              // 512 threads
  const double PI2 = 6.283185307179586476925286766559;
  if (i < 256){
    double a = PI2 * (double)i / 256.0;
    float c = (float)cos(a), s = (float)sin(a);
    t256f[i] = make_float2(c, -s);
    t256i[i] = make_float2(c,  s);
  }
  {
    double a = PI2 * (double)i / 512.0;
    float c = (float)cos(a), s = (float)sin(a);
    t512f[i] = make_float2(c, -s);
    t512i[i] = make_float2(c,  s);
  }
}

// ---------------- forward fft2 of x (naive DFTs, tiny) ----------------
__global__ void dft_m(const float* __restrict__ x, float2* __restrict__ Yw,
                      const float2* __restrict__ twf){
  __shared__ float xs[256];
  __shared__ float2 tws[256];
  int b = blockIdx.x, k = threadIdx.x;
  xs[k]  = x[b*256 + k];
  tws[k] = twf[k];
  __syncthreads();
  float yr = 0.f, yi = 0.f;
  for (int m = 0; m < 256; ++m){
    float2 w = tws[(m*k) & 255];
    float xv = xs[m];
    yr += xv*w.x; yi += xv*w.y;
  }
  Yw[b*256 + k] = make_float2(yr, yi);
}

__global__ void dft_b(const float2* __restrict__ Yw, float* __restrict__ Xr,
                      float* __restrict__ Xi, const float2* __restrict__ twf){
  __shared__ float2 tws[512];
  int j = blockIdx.x, k = threadIdx.x;
  tws[k]       = twf[k];
  tws[k + 256] = twf[k + 256];
  __syncthreads();
  float xr = 0.f, xi = 0.f;
  for (int b = 0; b < 512; ++b){
    float2 y = Yw[b*256 + k];
    float2 w = tws[(b*j) & 511];
    xr += y.x*w.x - y.y*w.y;
    xi += y.x*w.y + y.y*w.x;
  }
  Xr[j*256 + k] = xr;
  Xi[j*256 + k] = xi;
}

// ---------------- weight prep ----------------
// Wct[u][t] = sum_v lin1_w[u][v]*w1[t][v]; W2b[u][t] = lin2_w[u][t]  (bf16)
__global__ void prep_w(const float* __restrict__ w1, const float* __restrict__ lin1_w,
                       const float* __restrict__ lin2_w,
                       ushort_t* __restrict__ Wct, ushort_t* __restrict__ W2b){
  __shared__ float l1[256];
  int u = blockIdx.x, t = threadIdx.x;
  l1[t] = lin1_w[u*256 + t];
  __syncthreads();
  float s = 0.f;
  for (int v = 0; v < 256; ++v)
    s += l1[v] * w1[t*256 + v];
  Wct[u*256 + t] = f2bf(s);
  W2b[u*256 + t] = f2bf(lin2_w[u*256 + t]);
}

// ---------------- fused: h0 build + GEMM1 + GEMM2 + v-IFFT -> packed planes ----------------
__global__ __launch_bounds__(256)
void fused_mid(const float* __restrict__ Xr, const float* __restrict__ Xi,
               const float* __restrict__ w0,
               const ushort_t* __restrict__ Wct, const ushort_t* __restrict__ W2b,
               const float* __restrict__ b1, const float* __restrict__ b2,
               const float2* __restrict__ ph,      // e^{+2pi i k/256}
               uint_t* __restrict__ OutP)
{
  __shared__ __align__(16) char lds[65536];
  ushort_t* Bt = (ushort_t*)lds;              // [256][64] bf16, 32KB
  ushort_t* At = (ushort_t*)(lds + 32768);    // [64][64]  bf16,  8KB
  ushort_t* H3 = (ushort_t*)(lds + 32768);    // [64][256] bf16, 32KB (overlays At)
  float*    H4 = (float*)lds;                 // [64][256] f32,  64KB (overlays all)

  const int tid  = threadIdx.x;
  const int lane = tid & 63;
  const int wv   = tid >> 6;
  const int cr0  = blockIdx.x * 32;
  const int m0   = cr0 & 255;

  const int sr = tid >> 2;            // stacked row 0..63
  const int qq = tid & 3;
  const int jj = sr & 31;
  const float xr = Xr[cr0 + jj];
  const float xi = Xi[cr0 + jj];
  const float2 p = ph[m0 + jj];
  const bool isim = (sr >= 32);

  f32x4 acc[4][4];
  #pragma unroll
  for (int m = 0; m < 4; ++m)
    #pragma unroll
    for (int n = 0; n < 4; ++n)
      acc[m][n] = (f32x4){0.f,0.f,0.f,0.f};

  // ---------- GEMM1 ----------
  for (int kt = 0; kt < 4; ++kt){
    {
      const float4* w4 = (const float4*)&w0[(m0 + jj)*256 + kt*64 + qq*16];
      float4 f0 = w4[0], f1 = w4[1], f2 = w4[2], f3 = w4[3];
      float wvv[16] = {f0.x,f0.y,f0.z,f0.w, f1.x,f1.y,f1.z,f1.w,
                       f2.x,f2.y,f2.z,f2.w, f3.x,f3.y,f3.z,f3.w};
      uint_t pk[8];
      #pragma unroll
      for (int c = 0; c < 8; ++c){
        float wa = wvv[2*c], wb = wvv[2*c+1];
        float r0 = fmaxf(xr*wa, 0.f), i0 = fmaxf(xi*wa, 0.f);
        float r1 = fmaxf(xr*wb, 0.f), i1 = fmaxf(xi*wb, 0.f);
        float va = isim ? (p.y*r0 + p.x*i0) : (p.x*r0 - p.y*i0);
        float vb = isim ? (p.y*r1 + p.x*i1) : (p.x*r1 - p.y*i1);
        pk[c] = (uint_t)f2bf(va) | ((uint_t)f2bf(vb) << 16);
      }
      int s0 = (qq*2)     ^ (sr & 7);
      int s1 = (qq*2 + 1) ^ (sr & 7);
      *(uint4*)&At[sr*64 + s0*8] = make_uint4(pk[0],pk[1],pk[2],pk[3]);
      *(uint4*)&At[sr*64 + s1*8] = make_uint4(pk[4],pk[5],pk[6],pk[7]);
    }
    #pragma unroll
    for (int p8 = 0; p8 < 8; ++p8){
      int rl = wv*64 + p8*8 + (lane >> 3);
      int cs = (lane & 7) ^ (rl & 7);
      gld16(Wct + rl*256 + kt*64 + cs*8, &Bt[(wv*64 + p8*8)*64]);
    }
    __syncthreads();
    #pragma unroll
    for (int kk = 0; kk < 2; ++kk){
      short8b av[4], bv[4];
      #pragma unroll
      for (int m = 0; m < 4; ++m){
        int r = m*16 + (lane & 15);
        int s = (kk*4 + (lane >> 4)) ^ (r & 7);
        av[m] = *(const short8b*)&At[r*64 + s*8];
      }
      #pragma unroll
      for (int n = 0; n < 4; ++n){
        int c = wv*64 + n*16 + (lane & 15);
        int s = (kk*4 + (lane >> 4)) ^ (c & 7);
        bv[n] = *(const short8b*)&Bt[c*64 + s*8];
      }
      #pragma unroll
      for (int m = 0; m < 4; ++m)
        #pragma unroll
        for (int n = 0; n < 4; ++n)
          acc[m][n] = __builtin_amdgcn_mfma_f32_16x16x32_bf16(av[m], bv[n], acc[m][n], 0,0,0);
    }
    __syncthreads();
  }

  // ---------- epilogue1 -> H3 bf16 ----------
  const int cq = lane >> 4, cl = lane & 15;
  #pragma unroll
  for (int m = 0; m < 4; ++m){
    #pragma unroll
    for (int n = 0; n < 4; ++n){
      int col = wv*64 + n*16 + cl;
      #pragma unroll
      for (int q = 0; q < 4; ++q){
        int row = m*16 + cq*4 + q;
        float v = acc[m][n][q];
        if (row < 32) v += b1[col];
        v = fmaxf(v, 0.f);
        int s = (col >> 3) ^ (row & 7);
        H3[row*256 + s*8 + (col & 7)] = f2bf(v);
      }
    }
  }
  __syncthreads();

  // ---------- GEMM2 ----------
  #pragma unroll
  for (int m = 0; m < 4; ++m)
    #pragma unroll
    for (int n = 0; n < 4; ++n)
      acc[m][n] = (f32x4){0.f,0.f,0.f,0.f};

  for (int kt = 0; kt < 4; ++kt){
    #pragma unroll
    for (int p8 = 0; p8 < 8; ++p8){
      int rl = wv*64 + p8*8 + (lane >> 3);
      int cs = (lane & 7) ^ (rl & 7);
      gld16(W2b + rl*256 + kt*64 + cs*8, &Bt[(wv*64 + p8*8)*64]);
    }
    __syncthreads();
    #pragma unroll
    for (int kk = 0; kk < 2; ++kk){
      short8b av[4], bv[4];
      #pragma unroll
      for (int m = 0; m < 4; ++m){
        int r = m*16 + (lane & 15);
        int g = kt*8 + kk*4 + (lane >> 4);
        int s = g ^ (r & 7);
        av[m] = *(const short8b*)&H3[r*256 + s*8];
      }
      #pragma unroll
      for (int n = 0; n < 4; ++n){
        int c = wv*64 + n*16 + (lane & 15);
        int s = (kk*4 + (lane >> 4)) ^ (c & 7);
        bv[n] = *(const short8b*)&Bt[c*64 + s*8];
      }
      #pragma unroll
      for (int m = 0; m < 4; ++m)
        #pragma unroll
        for (int n = 0; n < 4; ++n)
          acc[m][n] = __builtin_amdgcn_mfma_f32_16x16x32_bf16(av[m], bv[n], acc[m][n], 0,0,0);
    }
    __syncthreads();
  }

  // ---------- epilogue2 -> H4 f32 ----------
  #pragma unroll
  for (int m = 0; m < 4; ++m){
    #pragma unroll
    for (int n = 0; n < 4; ++n){
      int col = wv*64 + n*16 + cl;
      #pragma unroll
      for (int q = 0; q < 4; ++q){
        int row = m*16 + cq*4 + q;
        float v = acc[m][n][q];
        if (row < 32) v += b2[col];
        H4[row*256 + col] = v;
      }
    }
  }
  __syncthreads();

  // ---------- v-axis inverse FFT (radix-2 DIF, natural in, bit-rev out) ----------
  {
    const int fj = tid >> 3;        // complex row 0..31
    const int s8 = tid & 7;
    float* Re = &H4[fj*256];
    float* Im = &H4[(fj+32)*256];
    #pragma unroll
    for (int e = 7; e >= 0; --e){
      int L = 1 << e;
      #pragma unroll
      for (int i = 0; i < 16; ++i){
        int t = s8 + i*8;
        int j = t & (L - 1);
        int i0 = ((t >> e) << (e + 1)) | j;
        int i1 = i0 + L;
        float2 w = ph[j << (7 - e)];
        float ar = Re[i0], ai = Im[i0], br = Re[i1], bi = Im[i1];
        float dr = ar - br, di = ai - bi;
        Re[i0] = ar + br; Im[i0] = ai + bi;
        Re[i1] = dr*w.x - di*w.y;
        Im[i1] = dr*w.y + di*w.x;
      }
      __syncthreads();
    }
  }
  // packed bf16 store (fold 1/256), natural v order via bit-reversed LDS read
  {
    int rv = __brev((unsigned)tid) >> 24;
    #pragma unroll
    for (int row = 0; row < 32; ++row){
      OutP[(long)(cr0 + row)*256 + tid] =
        pack_bf(H4[row*256 + rv]      * (1.f/256.f),
                H4[(row+32)*256 + rv] * (1.f/256.f));
    }
  }
}

// ---------------- m-axis IFFT (in-place on packed planes) ----------------
__global__ __launch_bounds__(1024)
void fft_m(uint_t* __restrict__ P, const float2* __restrict__ twg){
  __shared__ float Sr[4096], Si[4096];     // [mm][li] identity layout
  __shared__ float2 tw[128];
  int tid = threadIdx.x;
  int b = blockIdx.x >> 4, vg = blockIdx.x & 15;
  long base = (long)b*65536 + vg*16;
  #pragma unroll
  for (int c = 0; c < 4; ++c){
    int idx = tid + c*1024;
    int li = idx & 15, mm = idx >> 4;
    uint_t u = P[base + (long)mm*256 + li];
    Sr[idx] = bf_lo(u) * (1.f/256.f);
    Si[idx] = bf_hi(u) * (1.f/256.f);
  }
  if (tid < 128) tw[tid] = twg[tid];
  __syncthreads();
  int lp = tid & 7;          // li pair
  int t  = tid >> 3;         // butterfly id 0..127
  float2* R2 = (float2*)Sr;
  float2* I2 = (float2*)Si;
  #pragma unroll
  for (int e = 7; e >= 0; --e){
    int L = 1 << e;
    int j = t & (L - 1);
    int i0 = ((t >> e) << (e + 1)) | j;
    int i1 = i0 + L;
    float2 w = tw[j << (7 - e)];
    float2 ar = R2[i0*8+lp], ai = I2[i0*8+lp];
    float2 br = R2[i1*8+lp], bi = I2[i1*8+lp];
    float2 dr = make_float2(ar.x-br.x, ar.y-br.y);
    float2 di = make_float2(ai.x-bi.x, ai.y-bi.y);
    R2[i0*8+lp] = make_float2(ar.x+br.x, ar.y+br.y);
    I2[i0*8+lp] = make_float2(ai.x+bi.x, ai.y+bi.y);
    R2[i1*8+lp] = make_float2(dr.x*w.x - di.x*w.y, dr.y*w.x - di.y*w.y);
    I2[i1*8+lp] = make_float2(dr.x*w.y + di.x*w.x, dr.y*w.y + di.y*w.x);
    __syncthreads();
  }
  #pragma unroll
  for (int c = 0; c < 4; ++c){
    int idx = tid + c*1024;
    int li = idx & 15, mm = idx >> 4;
    int rv = __brev((unsigned)mm) >> 24;
    P[base + (long)mm*256 + li] = pack_bf(Sr[rv*16 + li], Si[rv*16 + li]);
  }
}

// ---------------- b-axis IFFT (in-place; writes REAL fp32 output) ----------------
__global__ __launch_bounds__(1024)
void fft_b(uint_t* __restrict__ P, const float2* __restrict__ twg){
  __shared__ float Sr[8192], Si[8192];     // [bb][li] identity, 64KB total
  int tid = threadIdx.x;
  int m = blockIdx.x >> 4, vg = blockIdx.x & 15;
  int base = m*256 + vg*16;
  #pragma unroll
  for (int c = 0; c < 8; ++c){
    int idx = tid + c*1024;
    int li = idx & 15, bb = idx >> 4;
    uint_t u = P[(long)bb*65536 + base + li];
    Sr[idx] = bf_lo(u) * (1.f/512.f);
    Si[idx] = bf_hi(u) * (1.f/512.f);
  }
  __syncthreads();
  int lp = tid & 7;
  int tq = tid >> 3;        // 0..127
  float2* R2 = (float2*)Sr;
  float2* I2 = (float2*)Si;
  #pragma unroll
  for (int e = 8; e >= 0; --e){
    int L = 1 << e;
    #pragma unroll
    for (int h = 0; h < 2; ++h){
      int t = tq + h*128;
      int j = t & (L - 1);
      int i0 = ((t >> e) << (e + 1)) | j;
      int i1 = i0 + L;
      float2 w = twg[j << (8 - e)];
      float2 ar = R2[i0*8+lp], ai = I2[i0*8+lp];
      float2 br = R2[i1*8+lp], bi = I2[i1*8+lp];
      float2 dr = make_float2(ar.x-br.x, ar.y-br.y);
      float2 di = make_float2(ai.x-bi.x, ai.y-bi.y);
      R2[i0*8+lp] = make_float2(ar.x+br.x, ar.y+br.y);
      I2[i0*8+lp] = make_float2(ai.x+bi.x, ai.y+bi.y);
      R2[i1*8+lp] = make_float2(dr.x*w.x - di.x*w.y, dr.y*w.x - di.y*w.y);
      I2[i1*8+lp] = make_float2(dr.x*w.y + di.x*w.x, dr.y*w.y + di.y*w.x);
    }
    __syncthreads();
  }
  float* out = (float*)P;
  #pragma unroll
  for (int c = 0; c < 8; ++c){
    int idx = tid + c*1024;
    int li = idx & 15, bb = idx >> 4;
    int rv = __brev((unsigned)bb) >> 23;
    out[(long)bb*65536 + base + li] = Sr[rv*16 + li];
  }
}

// ---------------- launch ----------------
extern "C" void kernel_launch(void* const* d_in, const int* in_sizes, int n_in,
                              void* d_out, int out_size, void* d_ws, size_t ws_size,
                              hipStream_t stream) {
  (void)in_sizes; (void)n_in; (void)out_size; (void)ws_size;
  const float* x      = (const float*)d_in[0];
  const float* w0     = (const float*)d_in[1];
  const float* w1     = (const float*)d_in[2];
  const float* lin1_w = (const float*)d_in[3];
  const float* lin1_b = (const float*)d_in[4];
  const float* lin2_w = (const float*)d_in[5];
  const float* lin2_b = (const float*)d_in[6];

  // ws smalls only (~2.5 MB)
  char* sm = (char*)d_ws;
  float2*   Yw     = (float2*)sm;   sm += 1048576;
  float*    Xr     = (float*)sm;    sm += 524288;
  float*    Xi     = (float*)sm;    sm += 524288;
  float2*   t256f  = (float2*)sm;   sm += 2048;
  float2*   t256i  = (float2*)sm;   sm += 2048;
  float2*   t512f  = (float2*)sm;   sm += 4096;
  float2*   t512i  = (float2*)sm;   sm += 4096;
  ushort_t* Wct    = (ushort_t*)sm; sm += 131072;
  ushort_t* W2b    = (ushort_t*)sm; sm += 131072;

  uint_t* planes = (uint_t*)d_out;    // packed bf16 complex, 33.5M x 4B = 134 MB

  fill_tables<<<1, 512, 0, stream>>>(t256f, t256i, t512f, t512i);
  dft_m<<<512, 256, 0, stream>>>(x, Yw, t256f);
  dft_b<<<512, 256, 0, stream>>>(Yw, Xr, Xi, t512f);
  prep_w<<<256, 256, 0, stream>>>(w1, lin1_w, lin2_w, Wct, W2b);
  fused_mid<<<4096, 256, 0, stream>>>(Xr, Xi, w0, Wct, W2b, lin1_b, lin2_b,
                                      t256i, planes);
  fft_m<<<8192, 1024, 0, stream>>>(planes, t256i);
  fft_b<<<4096, 1024, 0, stream>>>(planes, t512i);
}

// Round 4
// 454.108 us; speedup vs baseline: 1.3295x; 1.3295x over previous
//
#include <hip/hip_runtime.h>

// FNOBlock on MI355X — round 4: conflict-free four-step register FFTs.
//   d_out (134 MB) holds packed bf16 complex planes (uint32) between IFFT stages,
//   overwritten in-place by the final real fp32 output.
//   fused:  A=phase*crelu(X*w0) on the fly -> GEMM1(crelu,b1) -> GEMM2(b2)
//           -> v-axis IFFT (16x16 four-step, registers) -> packed planes in d_out
//   fft_m:  m-axis IFFT (16x16 four-step), in-place on packed planes
//   fft_b:  b-axis IFFT (32x16 four-step), in-place, writes REAL fp32 output

typedef unsigned short ushort_t;
typedef unsigned int   uint_t;
typedef __attribute__((ext_vector_type(8))) short short8b;   // 8 x bf16
typedef __attribute__((ext_vector_type(4))) float f32x4;

__device__ __forceinline__ ushort_t f2bf(float f){
  union { float f; uint_t u; } v; v.f = f;
  uint_t r = v.u + 0x7FFFu + ((v.u >> 16) & 1u);   // RNE
  return (ushort_t)(r >> 16);
}
__device__ __forceinline__ uint_t pack_bf(float re, float im){
  return (uint_t)f2bf(re) | ((uint_t)f2bf(im) << 16);
}
__device__ __forceinline__ float bf_lo(uint_t u){
  union { uint_t u; float f; } v; v.u = u << 16; return v.f;
}
__device__ __forceinline__ float bf_hi(uint_t u){
  union { uint_t u; float f; } v; v.u = u & 0xFFFF0000u; return v.f;
}
__device__ __forceinline__ void gld16(const void* g, void* l){
  __builtin_amdgcn_global_load_lds(
      (const __attribute__((address_space(1))) void*)g,
      (__attribute__((address_space(3))) void*)l, 16, 0, 0);
}

// ---------------- register FFTs (inverse sign, DIF, out[p] = X[brev(p)]) ----------------
constexpr int BR16T[16] = {0,8,4,12,2,10,6,14,1,9,5,13,3,11,7,15};
constexpr int BR32T[32] = {0,16,8,24,4,20,12,28,2,18,10,26,6,22,14,30,
                           1,17,9,25,5,21,13,29,3,19,11,27,7,23,15,31};

__device__ __forceinline__ void bfly(float& ar, float& ai, float& br, float& bi,
                                     float wr, float wi){
  float sr = ar - br, si = ai - bi;
  ar += br; ai += bi;
  br = sr*wr - si*wi;
  bi = sr*wi + si*wr;
}

__device__ __forceinline__ void fft16_inv(float* xr, float* xi){
  const float C1 = 0.92387953251128674f, S1 = 0.38268343236508978f,
              C2 = 0.70710678118654752f;
  bfly(xr[0],xi[0],xr[8],xi[8],    1.f, 0.f);
  bfly(xr[1],xi[1],xr[9],xi[9],    C1,  S1);
  bfly(xr[2],xi[2],xr[10],xi[10],  C2,  C2);
  bfly(xr[3],xi[3],xr[11],xi[11],  S1,  C1);
  bfly(xr[4],xi[4],xr[12],xi[12],  0.f, 1.f);
  bfly(xr[5],xi[5],xr[13],xi[13], -S1,  C1);
  bfly(xr[6],xi[6],xr[14],xi[14], -C2,  C2);
  bfly(xr[7],xi[7],xr[15],xi[15], -C1,  S1);
  #pragma unroll
  for (int h = 0; h < 16; h += 8){
    bfly(xr[h+0],xi[h+0],xr[h+4],xi[h+4],  1.f, 0.f);
    bfly(xr[h+1],xi[h+1],xr[h+5],xi[h+5],  C2,  C2);
    bfly(xr[h+2],xi[h+2],xr[h+6],xi[h+6],  0.f, 1.f);
    bfly(xr[h+3],xi[h+3],xr[h+7],xi[h+7], -C2,  C2);
  }
  #pragma unroll
  for (int h = 0; h < 16; h += 4){
    bfly(xr[h+0],xi[h+0],xr[h+2],xi[h+2], 1.f, 0.f);
    bfly(xr[h+1],xi[h+1],xr[h+3],xi[h+3], 0.f, 1.f);
  }
  #pragma unroll
  for (int h = 0; h < 16; h += 2)
    bfly(xr[h],xi[h],xr[h+1],xi[h+1], 1.f, 0.f);
}

__device__ __forceinline__ void fft32_inv(float* xr, float* xi){
  constexpr float WR[16] = {
    1.f, 0.98078528040323044f, 0.92387953251128674f, 0.83146961230254524f,
    0.70710678118654752f, 0.55557023301960222f, 0.38268343236508978f, 0.19509032201612827f,
    0.f,-0.19509032201612827f,-0.38268343236508978f,-0.55557023301960222f,
   -0.70710678118654752f,-0.83146961230254524f,-0.92387953251128674f,-0.98078528040323044f};
  constexpr float WI[16] = {
    0.f, 0.19509032201612827f, 0.38268343236508978f, 0.55557023301960222f,
    0.70710678118654752f, 0.83146961230254524f, 0.92387953251128674f, 0.98078528040323044f,
    1.f, 0.98078528040323044f, 0.92387953251128674f, 0.83146961230254524f,
    0.70710678118654752f, 0.55557023301960222f, 0.38268343236508978f, 0.19509032201612827f};
  #pragma unroll
  for (int j = 0; j < 16; ++j)
    bfly(xr[j],xi[j],xr[j+16],xi[j+16], WR[j], WI[j]);
  fft16_inv(xr, xi);
  fft16_inv(xr+16, xi+16);
}

// ---------------- tables ----------------
__global__ void fill_tables(float2* t256f, float2* t256i, float2* t512f, float2* t512i){
  int i = threadIdx.x;              // 512 threads
  const double PI2 = 6.283185307179586476925286766559;
  if (i < 256){
    double a = PI2 * (double)i / 256.0;
    float c = (float)cos(a), s = (float)sin(a);
    t256f[i] = make_float2(c, -s);
    t256i[i] = make_float2(c,  s);
  }
  {
    double a = PI2 * (double)i / 512.0;
    float c = (float)cos(a), s = (float)sin(a);
    t512f[i] = make_float2(c, -s);
    t512i[i] = make_float2(c,  s);
  }
}

// ---------------- forward fft2 of x (naive DFTs, tiny) ----------------
__global__ void dft_m(const float* __restrict__ x, float2* __restrict__ Yw,
                      const float2* __restrict__ twf){
  __shared__ float xs[256];
  __shared__ float2 tws[256];
  int b = blockIdx.x, k = threadIdx.x;
  xs[k]  = x[b*256 + k];
  tws[k] = twf[k];
  __syncthreads();
  float yr = 0.f, yi = 0.f;
  for (int m = 0; m < 256; ++m){
    float2 w = tws[(m*k) & 255];
    float xv = xs[m];
    yr += xv*w.x; yi += xv*w.y;
  }
  Yw[b*256 + k] = make_float2(yr, yi);
}

__global__ void dft_b(const float2* __restrict__ Yw, float* __restrict__ Xr,
                      float* __restrict__ Xi, const float2* __restrict__ twf){
  __shared__ float2 tws[512];
  int j = blockIdx.x, k = threadIdx.x;
  tws[k]       = twf[k];
  tws[k + 256] = twf[k + 256];
  __syncthreads();
  float xr = 0.f, xi = 0.f;
  for (int b = 0; b < 512; ++b){
    float2 y = Yw[b*256 + k];
    float2 w = tws[(b*j) & 511];
    xr += y.x*w.x - y.y*w.y;
    xi += y.x*w.y + y.y*w.x;
  }
  Xr[j*256 + k] = xr;
  Xi[j*256 + k] = xi;
}

// ---------------- weight prep ----------------
__global__ void prep_w(const float* __restrict__ w1, const float* __restrict__ lin1_w,
                       const float* __restrict__ lin2_w,
                       ushort_t* __restrict__ Wct, ushort_t* __restrict__ W2b){
  __shared__ float l1[256];
  int u = blockIdx.x, t = threadIdx.x;
  l1[t] = lin1_w[u*256 + t];
  __syncthreads();
  float s = 0.f;
  for (int v = 0; v < 256; ++v)
    s += l1[v] * w1[t*256 + v];
  Wct[u*256 + t] = f2bf(s);
  W2b[u*256 + t] = f2bf(lin2_w[u*256 + t]);
}

// ---------------- fused: h0 build + GEMM1 + GEMM2 + v-IFFT -> packed planes ----------------
__global__ __launch_bounds__(256)
void fused_mid(const float* __restrict__ Xr, const float* __restrict__ Xi,
               const float* __restrict__ w0,
               const ushort_t* __restrict__ Wct, const ushort_t* __restrict__ W2b,
               const float* __restrict__ b1, const float* __restrict__ b2,
               const float2* __restrict__ ph,      // e^{+2pi i k/256}
               uint_t* __restrict__ OutP)
{
  __shared__ __align__(16) char lds[65536];
  ushort_t* Bt  = (ushort_t*)lds;              // [256][64] bf16, 32KB
  ushort_t* At  = (ushort_t*)(lds + 32768);    // [64][64]  bf16,  8KB
  ushort_t* H3  = (ushort_t*)(lds + 32768);    // [64][256] bf16, 32KB (overlays At)
  float2*   H4c = (float2*)lds;                // [32][256] complex, 64KB (overlays all)

  const int tid  = threadIdx.x;
  const int lane = tid & 63;
  const int wv   = tid >> 6;
  const int cr0  = blockIdx.x * 32;
  const int m0   = cr0 & 255;

  const int sr = tid >> 2;            // stacked row 0..63
  const int qq = tid & 3;
  const int jj = sr & 31;
  const float xr0 = Xr[cr0 + jj];
  const float xi0 = Xi[cr0 + jj];
  const float2 pj = ph[m0 + jj];
  const bool isim = (sr >= 32);

  f32x4 acc[4][4];
  #pragma unroll
  for (int m = 0; m < 4; ++m)
    #pragma unroll
    for (int n = 0; n < 4; ++n)
      acc[m][n] = (f32x4){0.f,0.f,0.f,0.f};

  // ---------- GEMM1 ----------
  for (int kt = 0; kt < 4; ++kt){
    {
      const float4* w4 = (const float4*)&w0[(m0 + jj)*256 + kt*64 + qq*16];
      float4 f0 = w4[0], f1 = w4[1], f2 = w4[2], f3 = w4[3];
      float wvv[16] = {f0.x,f0.y,f0.z,f0.w, f1.x,f1.y,f1.z,f1.w,
                       f2.x,f2.y,f2.z,f2.w, f3.x,f3.y,f3.z,f3.w};
      uint_t pk[8];
      #pragma unroll
      for (int c = 0; c < 8; ++c){
        float wa = wvv[2*c], wb = wvv[2*c+1];
        float r0 = fmaxf(xr0*wa, 0.f), i0 = fmaxf(xi0*wa, 0.f);
        float r1 = fmaxf(xr0*wb, 0.f), i1 = fmaxf(xi0*wb, 0.f);
        float va = isim ? (pj.y*r0 + pj.x*i0) : (pj.x*r0 - pj.y*i0);
        float vb = isim ? (pj.y*r1 + pj.x*i1) : (pj.x*r1 - pj.y*i1);
        pk[c] = (uint_t)f2bf(va) | ((uint_t)f2bf(vb) << 16);
      }
      int s0 = (qq*2)     ^ (sr & 7);
      int s1 = (qq*2 + 1) ^ (sr & 7);
      *(uint4*)&At[sr*64 + s0*8] = make_uint4(pk[0],pk[1],pk[2],pk[3]);
      *(uint4*)&At[sr*64 + s1*8] = make_uint4(pk[4],pk[5],pk[6],pk[7]);
    }
    #pragma unroll
    for (int p8 = 0; p8 < 8; ++p8){
      int rl = wv*64 + p8*8 + (lane >> 3);
      int cs = (lane & 7) ^ (rl & 7);
      gld16(Wct + rl*256 + kt*64 + cs*8, &Bt[(wv*64 + p8*8)*64]);
    }
    __syncthreads();
    #pragma unroll
    for (int kk = 0; kk < 2; ++kk){
      short8b av[4], bv[4];
      #pragma unroll
      for (int m = 0; m < 4; ++m){
        int r = m*16 + (lane & 15);
        int s = (kk*4 + (lane >> 4)) ^ (r & 7);
        av[m] = *(const short8b*)&At[r*64 + s*8];
      }
      #pragma unroll
      for (int n = 0; n < 4; ++n){
        int c = wv*64 + n*16 + (lane & 15);
        int s = (kk*4 + (lane >> 4)) ^ (c & 7);
        bv[n] = *(const short8b*)&Bt[c*64 + s*8];
      }
      #pragma unroll
      for (int m = 0; m < 4; ++m)
        #pragma unroll
        for (int n = 0; n < 4; ++n)
          acc[m][n] = __builtin_amdgcn_mfma_f32_16x16x32_bf16(av[m], bv[n], acc[m][n], 0,0,0);
    }
    __syncthreads();
  }

  // ---------- epilogue1 -> H3 bf16 ----------
  const int cq = lane >> 4, cl = lane & 15;
  #pragma unroll
  for (int m = 0; m < 4; ++m){
    #pragma unroll
    for (int n = 0; n < 4; ++n){
      int col = wv*64 + n*16 + cl;
      #pragma unroll
      for (int q = 0; q < 4; ++q){
        int row = m*16 + cq*4 + q;
        float v = acc[m][n][q];
        if (row < 32) v += b1[col];
        v = fmaxf(v, 0.f);
        int s = (col >> 3) ^ (row & 7);
        H3[row*256 + s*8 + (col & 7)] = f2bf(v);
      }
    }
  }
  __syncthreads();

  // ---------- GEMM2 ----------
  #pragma unroll
  for (int m = 0; m < 4; ++m)
    #pragma unroll
    for (int n = 0; n < 4; ++n)
      acc[m][n] = (f32x4){0.f,0.f,0.f,0.f};

  for (int kt = 0; kt < 4; ++kt){
    #pragma unroll
    for (int p8 = 0; p8 < 8; ++p8){
      int rl = wv*64 + p8*8 + (lane >> 3);
      int cs = (lane & 7) ^ (rl & 7);
      gld16(W2b + rl*256 + kt*64 + cs*8, &Bt[(wv*64 + p8*8)*64]);
    }
    __syncthreads();
    #pragma unroll
    for (int kk = 0; kk < 2; ++kk){
      short8b av[4], bv[4];
      #pragma unroll
      for (int m = 0; m < 4; ++m){
        int r = m*16 + (lane & 15);
        int g = kt*8 + kk*4 + (lane >> 4);
        int s = g ^ (r & 7);
        av[m] = *(const short8b*)&H3[r*256 + s*8];
      }
      #pragma unroll
      for (int n = 0; n < 4; ++n){
        int c = wv*64 + n*16 + (lane & 15);
        int s = (kk*4 + (lane >> 4)) ^ (c & 7);
        bv[n] = *(const short8b*)&Bt[c*64 + s*8];
      }
      #pragma unroll
      for (int m = 0; m < 4; ++m)
        #pragma unroll
        for (int n = 0; n < 4; ++n)
          acc[m][n] = __builtin_amdgcn_mfma_f32_16x16x32_bf16(av[m], bv[n], acc[m][n], 0,0,0);
    }
    __syncthreads();
  }

  // ---------- epilogue2: complex rows r=m2*16+cq*4+q; re=acc[m2], im=acc[m2+2] ----------
  // fold the v-pass 1/256 normalization here
  #pragma unroll
  for (int m2 = 0; m2 < 2; ++m2){
    #pragma unroll
    for (int n = 0; n < 4; ++n){
      int col = wv*64 + n*16 + cl;
      #pragma unroll
      for (int q = 0; q < 4; ++q){
        int r = m2*16 + cq*4 + q;
        float vr = (acc[m2][n][q]   + b2[col]) * (1.f/256.f);
        float vi =  acc[m2+2][n][q]            * (1.f/256.f);
        H4c[r*256 + col] = make_float2(vr, vi);
      }
    }
  }
  __syncthreads();

  // ---------- v-axis inverse FFT: 16x16 four-step in registers ----------
  {
    const int b16 = tid & 15;
    const int rp  = tid >> 4;           // rows rp and rp+16
    float ar[2][16], ai[2][16];
    #pragma unroll
    for (int h = 0; h < 2; ++h){
      int r = rp + h*16;
      #pragma unroll
      for (int a = 0; a < 16; ++a){
        float2 u = H4c[r*256 + a*16 + b16];
        ar[h][a] = u.x; ai[h][a] = u.y;
      }
    }
    __syncthreads();                    // all reads done; LDS becomes Z
    float2 ws = ph[b16];
    #pragma unroll
    for (int h = 0; h < 2; ++h){
      int r = rp + h*16;
      fft16_inv(ar[h], ai[h]);
      float wr = 1.f, wi = 0.f;
      #pragma unroll
      for (int d = 0; d < 16; ++d){
        float yr = ar[h][BR16T[d]], yi = ai[h][BR16T[d]];
        H4c[r*256 + d*16 + ((b16 + d) & 15)] =
            make_float2(yr*wr - yi*wi, yr*wi + yi*wr);
        float nw = wr*ws.x - wi*ws.y;
        wi = wr*ws.y + wi*ws.x; wr = nw;
      }
    }
    __syncthreads();
    const int d = tid & 15;
    #pragma unroll
    for (int h = 0; h < 2; ++h){
      int r = rp + h*16;
      float br2[16], bi2[16];
      #pragma unroll
      for (int b = 0; b < 16; ++b){
        float2 u = H4c[r*256 + d*16 + ((b + d) & 15)];
        br2[b] = u.x; bi2[b] = u.y;
      }
      fft16_inv(br2, bi2);
      #pragma unroll
      for (int p = 0; p < 16; ++p){
        int k = BR16T[p]*16 + d;
        OutP[(long)(cr0 + r)*256 + k] = pack_bf(br2[p], bi2[p]);
      }
    }
  }
}

// ---------------- m-axis IFFT: 16x16 four-step, in-place on packed planes ----------------
__global__ __launch_bounds__(256)
void fft_m(uint_t* __restrict__ P, const float2* __restrict__ ph){
  __shared__ float2 Z[4096];            // [16 d][16 rot][16 v] = 32KB
  const int tid = threadIdx.x;
  const int v   = tid & 15;
  const int b16 = tid >> 4;
  const int bB  = blockIdx.x >> 4;
  const int vg  = (blockIdx.x & 15) << 4;
  const long base = (long)bB*65536 + vg + v;

  float xr[16], xi[16];
  #pragma unroll
  for (int a = 0; a < 16; ++a){
    uint_t u = P[base + (long)(a*16 + b16)*256];
    xr[a] = bf_lo(u) * (1.f/256.f);
    xi[a] = bf_hi(u) * (1.f/256.f);
  }
  fft16_inv(xr, xi);
  float2 ws = ph[b16];
  float wr = 1.f, wi = 0.f;
  #pragma unroll
  for (int d = 0; d < 16; ++d){
    float yr = xr[BR16T[d]], yi = xi[BR16T[d]];
    Z[(d*16 + ((b16 + d) & 15))*16 + v] =
        make_float2(yr*wr - yi*wi, yr*wi + yi*wr);
    float nw = wr*ws.x - wi*ws.y;
    wi = wr*ws.y + wi*ws.x; wr = nw;
  }
  __syncthreads();
  const int d = b16;
  float br2[16], bi2[16];
  #pragma unroll
  for (int b = 0; b < 16; ++b){
    float2 u = Z[(d*16 + ((b + d) & 15))*16 + v];
    br2[b] = u.x; bi2[b] = u.y;
  }
  fft16_inv(br2, bi2);
  #pragma unroll
  for (int p = 0; p < 16; ++p){
    int k = BR16T[p]*16 + d;
    P[base + (long)k*256] = pack_bf(br2[p], bi2[p]);
  }
}

// ---------------- b-axis IFFT: 32x16 four-step, in-place, REAL fp32 out ----------------
__global__ __launch_bounds__(256)
void fft_b(uint_t* __restrict__ P, const float2* __restrict__ t512){
  __shared__ float2 Z[8192];            // [32 d][16 rot][16 v] = 64KB
  const int tid = threadIdx.x;
  const int v   = tid & 15;
  const int b16 = tid >> 4;
  const int m   = blockIdx.x >> 4;
  const int vg  = (blockIdx.x & 15) << 4;
  const long base = (long)m*256 + vg + v;

  float xr[32], xi[32];
  #pragma unroll
  for (int a = 0; a < 32; ++a){
    uint_t u = P[base + (long)(a*16 + b16)*65536];
    xr[a] = bf_lo(u) * (1.f/512.f);
    xi[a] = bf_hi(u) * (1.f/512.f);
  }
  fft32_inv(xr, xi);
  float2 ws = t512[b16];
  float wr = 1.f, wi = 0.f;
  #pragma unroll
  for (int d = 0; d < 32; ++d){
    float yr = xr[BR32T[d]], yi = xi[BR32T[d]];
    Z[(d*16 + ((b16 + d) & 15))*16 + v] =
        make_float2(yr*wr - yi*wi, yr*wi + yi*wr);
    float nw = wr*ws.x - wi*ws.y;
    wi = wr*ws.y + wi*ws.x; wr = nw;
  }
  __syncthreads();
  float* out = (float*)P;
  #pragma unroll
  for (int h = 0; h < 2; ++h){
    const int d = b16 + h*16;
    float br2[16], bi2[16];
    #pragma unroll
    for (int b = 0; b < 16; ++b){
      float2 u = Z[(d*16 + ((b + d) & 15))*16 + v];
      br2[b] = u.x; bi2[b] = u.y;
    }
    fft16_inv(br2, bi2);
    #pragma unroll
    for (int p = 0; p < 16; ++p){
      int k = BR16T[p]*32 + d;           // bb = 32c + d
      out[base + (long)k*65536] = br2[p];
    }
  }
}

// ---------------- launch ----------------
extern "C" void kernel_launch(void* const* d_in, const int* in_sizes, int n_in,
                              void* d_out, int out_size, void* d_ws, size_t ws_size,
                              hipStream_t stream) {
  (void)in_sizes; (void)n_in; (void)out_size; (void)ws_size;
  const float* x      = (const float*)d_in[0];
  const float* w0     = (const float*)d_in[1];
  const float* w1     = (const float*)d_in[2];
  const float* lin1_w = (const float*)d_in[3];
  const float* lin1_b = (const float*)d_in[4];
  const float* lin2_w = (const float*)d_in[5];
  const float* lin2_b = (const float*)d_in[6];

  // ws smalls only (~2.5 MB)
  char* sm = (char*)d_ws;
  float2*   Yw     = (float2*)sm;   sm += 1048576;
  float*    Xr     = (float*)sm;    sm += 524288;
  float*    Xi     = (float*)sm;    sm += 524288;
  float2*   t256f  = (float2*)sm;   sm += 2048;
  float2*   t256i  = (float2*)sm;   sm += 2048;
  float2*   t512f  = (float2*)sm;   sm += 4096;
  float2*   t512i  = (float2*)sm;   sm += 4096;
  ushort_t* Wct    = (ushort_t*)sm; sm += 131072;
  ushort_t* W2b    = (ushort_t*)sm; sm += 131072;

  uint_t* planes = (uint_t*)d_out;    // packed bf16 complex planes, 134 MB

  fill_tables<<<1, 512, 0, stream>>>(t256f, t256i, t512f, t512i);
  dft_m<<<512, 256, 0, stream>>>(x, Yw, t256f);
  dft_b<<<512, 256, 0, stream>>>(Yw, Xr, Xi, t512f);
  prep_w<<<256, 256, 0, stream>>>(w1, lin1_w, lin2_w, Wct, W2b);
  fused_mid<<<4096, 256, 0, stream>>>(Xr, Xi, w0, Wct, W2b, lin1_b, lin2_b,
                                      t256i, planes);
  fft_m<<<8192, 256, 0, stream>>>(planes, t256i);
  fft_b<<<4096, 256, 0, stream>>>(planes, t512i);
}

// Round 5
// 320.284 us; speedup vs baseline: 1.8849x; 1.4178x over previous
//
#include <hip/hip_runtime.h>
#include <hip/hip_bf16.h>

// FNOBlock on MI355X — round 5: dbuf GEMM pipeline + hw bf16 cvt + padded-stride FFT layouts.
//   d_out (134 MB) holds packed bf16 complex planes (uint32) between IFFT stages,
//   overwritten in-place by the final real fp32 output.

typedef unsigned short ushort_t;
typedef unsigned int   uint_t;
typedef __attribute__((ext_vector_type(8))) short short8b;   // 8 x bf16
typedef __attribute__((ext_vector_type(4))) float f32x4;

__device__ __forceinline__ uint_t packf2(float lo, float hi){
  union { __hip_bfloat162 h; uint_t u; } v;
  v.h = __float22bfloat162_rn(make_float2(lo, hi));
  return v.u;
}
__device__ __forceinline__ ushort_t f2bf(float f){
  union { __hip_bfloat16 h; ushort_t u; } v;
  v.h = __float2bfloat16(f);
  return v.u;
}
__device__ __forceinline__ float bf_lo(uint_t u){
  union { uint_t u; float f; } v; v.u = u << 16; return v.f;
}
__device__ __forceinline__ float bf_hi(uint_t u){
  union { uint_t u; float f; } v; v.u = u & 0xFFFF0000u; return v.f;
}
__device__ __forceinline__ void gld16(const void* g, void* l){
  __builtin_amdgcn_global_load_lds(
      (const __attribute__((address_space(1))) void*)g,
      (__attribute__((address_space(3))) void*)l, 16, 0, 0);
}

// ---------------- register FFTs (inverse sign, DIF, out[p] = X[brev(p)]) ----------------
constexpr int BR16T[16] = {0,8,4,12,2,10,6,14,1,9,5,13,3,11,7,15};
constexpr int BR32T[32] = {0,16,8,24,4,20,12,28,2,18,10,26,6,22,14,30,
                           1,17,9,25,5,21,13,29,3,19,11,27,7,23,15,31};

__device__ __forceinline__ void bfly(float& ar, float& ai, float& br, float& bi,
                                     float wr, float wi){
  float sr = ar - br, si = ai - bi;
  ar += br; ai += bi;
  br = sr*wr - si*wi;
  bi = sr*wi + si*wr;
}

__device__ __forceinline__ void fft16_inv(float* xr, float* xi){
  const float C1 = 0.92387953251128674f, S1 = 0.38268343236508978f,
              C2 = 0.70710678118654752f;
  bfly(xr[0],xi[0],xr[8],xi[8],    1.f, 0.f);
  bfly(xr[1],xi[1],xr[9],xi[9],    C1,  S1);
  bfly(xr[2],xi[2],xr[10],xi[10],  C2,  C2);
  bfly(xr[3],xi[3],xr[11],xi[11],  S1,  C1);
  bfly(xr[4],xi[4],xr[12],xi[12],  0.f, 1.f);
  bfly(xr[5],xi[5],xr[13],xi[13], -S1,  C1);
  bfly(xr[6],xi[6],xr[14],xi[14], -C2,  C2);
  bfly(xr[7],xi[7],xr[15],xi[15], -C1,  S1);
  #pragma unroll
  for (int h = 0; h < 16; h += 8){
    bfly(xr[h+0],xi[h+0],xr[h+4],xi[h+4],  1.f, 0.f);
    bfly(xr[h+1],xi[h+1],xr[h+5],xi[h+5],  C2,  C2);
    bfly(xr[h+2],xi[h+2],xr[h+6],xi[h+6],  0.f, 1.f);
    bfly(xr[h+3],xi[h+3],xr[h+7],xi[h+7], -C2,  C2);
  }
  #pragma unroll
  for (int h = 0; h < 16; h += 4){
    bfly(xr[h+0],xi[h+0],xr[h+2],xi[h+2], 1.f, 0.f);
    bfly(xr[h+1],xi[h+1],xr[h+3],xi[h+3], 0.f, 1.f);
  }
  #pragma unroll
  for (int h = 0; h < 16; h += 2)
    bfly(xr[h],xi[h],xr[h+1],xi[h+1], 1.f, 0.f);
}

__device__ __forceinline__ void fft32_inv(float* xr, float* xi){
  constexpr float WR[16] = {
    1.f, 0.98078528040323044f, 0.92387953251128674f, 0.83146961230254524f,
    0.70710678118654752f, 0.55557023301960222f, 0.38268343236508978f, 0.19509032201612827f,
    0.f,-0.19509032201612827f,-0.38268343236508978f,-0.55557023301960222f,
   -0.70710678118654752f,-0.83146961230254524f,-0.92387953251128674f,-0.98078528040323044f};
  constexpr float WI[16] = {
    0.f, 0.19509032201612827f, 0.38268343236508978f, 0.55557023301960222f,
    0.70710678118654752f, 0.83146961230254524f, 0.92387953251128674f, 0.98078528040323044f,
    1.f, 0.98078528040323044f, 0.92387953251128674f, 0.83146961230254524f,
    0.70710678118654752f, 0.55557023301960222f, 0.38268343236508978f, 0.19509032201612827f};
  #pragma unroll
  for (int j = 0; j < 16; ++j)
    bfly(xr[j],xi[j],xr[j+16],xi[j+16], WR[j], WI[j]);
  fft16_inv(xr, xi);
  fft16_inv(xr+16, xi+16);
}

// ---------------- tables ----------------
__global__ void fill_tables(float2* t256f, float2* t256i, float2* t512f, float2* t512i){
  int i = threadIdx.x;              // 512 threads
  const double PI2 = 6.283185307179586476925286766559;
  if (i < 256){
    double a = PI2 * (double)i / 256.0;
    float c = (float)cos(a), s = (float)sin(a);
    t256f[i] = make_float2(c, -s);
    t256i[i] = make_float2(c,  s);
  }
  {
    double a = PI2 * (double)i / 512.0;
    float c = (float)cos(a), s = (float)sin(a);
    t512f[i] = make_float2(c, -s);
    t512i[i] = make_float2(c,  s);
  }
}

// ---------------- forward fft2 of x (naive DFTs, tiny) ----------------
__global__ void dft_m(const float* __restrict__ x, float2* __restrict__ Yw,
                      const float2* __restrict__ twf){
  __shared__ float xs[256];
  __shared__ float2 tws[256];
  int b = blockIdx.x, k = threadIdx.x;
  xs[k]  = x[b*256 + k];
  tws[k] = twf[k];
  __syncthreads();
  float yr = 0.f, yi = 0.f;
  for (int m = 0; m < 256; ++m){
    float2 w = tws[(m*k) & 255];
    float xv = xs[m];
    yr += xv*w.x; yi += xv*w.y;
  }
  Yw[b*256 + k] = make_float2(yr, yi);
}

__global__ void dft_b(const float2* __restrict__ Yw, float* __restrict__ Xr,
                      float* __restrict__ Xi, const float2* __restrict__ twf){
  __shared__ float2 tws[512];
  int j = blockIdx.x, k = threadIdx.x;
  tws[k]       = twf[k];
  tws[k + 256] = twf[k + 256];
  __syncthreads();
  float xr = 0.f, xi = 0.f;
  for (int b = 0; b < 512; ++b){
    float2 y = Yw[b*256 + k];
    float2 w = tws[(b*j) & 511];
    xr += y.x*w.x - y.y*w.y;
    xi += y.x*w.y + y.y*w.x;
  }
  Xr[j*256 + k] = xr;
  Xi[j*256 + k] = xi;
}

// ---------------- weight prep ----------------
__global__ void prep_w(const float* __restrict__ w1, const float* __restrict__ lin1_w,
                       const float* __restrict__ lin2_w,
                       ushort_t* __restrict__ Wct, ushort_t* __restrict__ W2b){
  __shared__ float l1[256];
  int u = blockIdx.x, t = threadIdx.x;
  l1[t] = lin1_w[u*256 + t];
  __syncthreads();
  float s = 0.f;
  for (int v = 0; v < 256; ++v)
    s += l1[v] * w1[t*256 + v];
  Wct[u*256 + t] = f2bf(s);
  W2b[u*256 + t] = f2bf(lin2_w[u*256 + t]);
}

// ---------------- fused: h0 build + GEMM1 + GEMM2 + v-IFFT -> packed planes ----------------
// 512 threads (8 waves), 32 complex rows per block (stacked rows: [re 0..31][im 32..63]).
// Wave w owns output cols [32w, 32w+32). K-step 32, A/B double-buffered.
// LDS (64 KB): [Bt dbuf 0..32K][At dbuf 32K..40K / H3 32K..64K]; Z (38 KB) overlays post-GEMM2.
#define ZJS 300   // Z j-stride (uints): mult of 4 (b128 align), %32=12 (bank spread)

__global__ __launch_bounds__(512, 4)
void fused_mid(const float* __restrict__ Xr, const float* __restrict__ Xi,
               const float* __restrict__ w0,
               const ushort_t* __restrict__ Wct, const ushort_t* __restrict__ W2b,
               const float* __restrict__ b1, const float* __restrict__ b2,
               const float2* __restrict__ ph,      // e^{+2pi i k/256}
               uint_t* __restrict__ OutP)
{
  __shared__ __align__(16) char lds[65536];
  ushort_t* H3 = (ushort_t*)(lds + 32768);   // [64][256] bf16 (after GEMM1)
  uint_t*   Z  = (uint_t*)lds;               // post-GEMM2 overlay

  const int tid  = threadIdx.x;
  const int lane = tid & 63;
  const int w8   = tid >> 6;          // wave 0..7
  const int L    = lane & 15;
  const int chk  = lane >> 4;         // 0..3 (k-chunk / C-row-quad)
  const int cq   = chk, cl = L;
  const int cr0  = blockIdx.x * 32;

  // ---- A-build constants (thread builds 4 bf16 of the A tile per kt) ----
  const int arow = tid >> 3;           // stacked row 0..63
  const int ak0  = (tid & 7) * 4;      // k within 32-tile
  const int ajj  = arow & 31;
  const bool aim = arow >= 32;
  const float axr = Xr[cr0 + ajj];
  const float axi = Xi[cr0 + ajj];
  const float2 apj = ph[(cr0 + ajj) & 255];
  const int am = (cr0 + ajj) & 255;    // w0 row (mode)
  const int aslot = (ak0 >> 3) ^ ((arow >> 1) & 3);
  const int aoff  = arow*64 + aslot*16 + (ak0 & 7)*2;   // byte offset in At buffer

  // ---- fragment read indices (ushort units) ----
  const int fsl  = chk ^ ((L >> 1) & 3);
  const int avix = L*32 + fsl*8;             // + m*512
  const int bvix = w8*1024 + avix;           // + n*512

  // ---- B staging constants (2 gld16/thread) ----
  const int bc = (tid & 3) ^ ((tid >> 3) & 3);   // source k-chunk for this slot

  f32x4 acc[4][2];
  #pragma unroll
  for (int m = 0; m < 4; ++m)
    #pragma unroll
    for (int n = 0; n < 2; ++n)
      acc[m][n] = (f32x4){0.f,0.f,0.f,0.f};

  #define STAGE_B(W, kt, bsel) do {                                        \
    char* _d = lds + (bsel)*16384 + tid*16;                                \
    _Pragma("unroll")                                                      \
    for (int _i = 0; _i < 2; ++_i){                                        \
      int _row = _i*128 + (tid >> 2);                                      \
      gld16((W) + _row*256 + (kt)*32 + bc*8, _d + _i*8192);                \
    }                                                                      \
  } while(0)

  #define STAGE_A(kt, bsel) do {                                           \
    const float4 _w4 = *(const float4*)&w0[(size_t)am*256 + (kt)*32 + ak0];\
    float _wv[4] = {_w4.x, _w4.y, _w4.z, _w4.w};                           \
    float _va[4];                                                          \
    _Pragma("unroll")                                                      \
    for (int _e = 0; _e < 4; ++_e){                                        \
      float _r = fmaxf(axr*_wv[_e], 0.f);                                  \
      float _m = fmaxf(axi*_wv[_e], 0.f);                                  \
      _va[_e] = aim ? (apj.y*_r + apj.x*_m) : (apj.x*_r - apj.y*_m);       \
    }                                                                      \
    *(uint2*)(lds + 32768 + (bsel)*4096 + aoff) =                          \
        make_uint2(packf2(_va[0], _va[1]), packf2(_va[2], _va[3]));        \
  } while(0)

  // ---------- GEMM1: acc = A(64x256) @ Wct^T ----------
  int buf = 0;
  STAGE_B(Wct, 0, 0);
  STAGE_A(0, 0);
  __syncthreads();
  for (int kt = 0; kt < 8; ++kt){
    if (kt < 7){ STAGE_B(Wct, kt+1, buf^1); STAGE_A(kt+1, buf^1); }
    const ushort_t* Ab = (const ushort_t*)(lds + 32768 + buf*4096);
    const ushort_t* Bb = (const ushort_t*)(lds + buf*16384);
    short8b av[4], bv[2];
    #pragma unroll
    for (int m = 0; m < 4; ++m) av[m] = *(const short8b*)&Ab[avix + m*512];
    #pragma unroll
    for (int n = 0; n < 2; ++n) bv[n] = *(const short8b*)&Bb[bvix + n*512];
    #pragma unroll
    for (int m = 0; m < 4; ++m)
      #pragma unroll
      for (int n = 0; n < 2; ++n)
        acc[m][n] = __builtin_amdgcn_mfma_f32_16x16x32_bf16(av[m], bv[n], acc[m][n], 0,0,0);
    __syncthreads();
    buf ^= 1;
  }

  // ---------- epilogue1: h3 = relu(acc + b1(re rows)) -> H3 bf16 (swizzled) ----------
  STAGE_B(W2b, 0, 0);      // prefetch GEMM2 kt=0 under the epilogue
  #pragma unroll
  for (int m = 0; m < 4; ++m){
    #pragma unroll
    for (int n = 0; n < 2; ++n){
      int col = w8*32 + n*16 + cl;
      float badd = (m < 2) ? b1[col] : 0.f;
      #pragma unroll
      for (int q = 0; q < 4; ++q){
        int row = m*16 + cq*4 + q;
        float v = fmaxf(acc[m][n][q] + badd, 0.f);
        int s = (col >> 3) ^ (row & 7);
        H3[row*256 + s*8 + (col & 7)] = f2bf(v);
      }
    }
  }
  __syncthreads();

  // ---------- GEMM2: acc = H3(64x256) @ W2b^T ----------
  #pragma unroll
  for (int m = 0; m < 4; ++m)
    #pragma unroll
    for (int n = 0; n < 2; ++n)
      acc[m][n] = (f32x4){0.f,0.f,0.f,0.f};

  buf = 0;
  for (int kt = 0; kt < 8; ++kt){
    if (kt < 7) STAGE_B(W2b, kt+1, buf^1);
    const ushort_t* Bb = (const ushort_t*)(lds + buf*16384);
    short8b av[4], bv[2];
    #pragma unroll
    for (int m = 0; m < 4; ++m){
      int r = m*16 + L;
      int s = (kt*4 + chk) ^ (r & 7);
      av[m] = *(const short8b*)&H3[r*256 + s*8];
    }
    #pragma unroll
    for (int n = 0; n < 2; ++n) bv[n] = *(const short8b*)&Bb[bvix + n*512];
    #pragma unroll
    for (int m = 0; m < 4; ++m)
      #pragma unroll
      for (int n = 0; n < 2; ++n)
        acc[m][n] = __builtin_amdgcn_mfma_f32_16x16x32_bf16(av[m], bv[n], acc[m][n], 0,0,0);
    __syncthreads();
    buf ^= 1;
  }

  // ---------- epilogue2: h4 packed bf16 -> Z[j][a][b] (j-stride ZJS) ----------
  #pragma unroll
  for (int m2 = 0; m2 < 2; ++m2){
    #pragma unroll
    for (int n = 0; n < 2; ++n){
      int col = w8*32 + n*16 + cl;
      float bias2 = b2[col];
      int a = col >> 4;                       // 2*w8 + n
      #pragma unroll
      for (int q = 0; q < 4; ++q){
        int j = m2*16 + cq*4 + q;
        Z[j*ZJS + a*16 + cl] = packf2(acc[m2][n][q] + bias2, acc[m2+2][n][q]);
      }
    }
  }
  __syncthreads();

  // ---------- v-IFFT stage 1: FFT16 over a, twiddle, in-place (column-private) ----------
  {
    const int j1 = tid >> 4;       // 0..31
    const int b1c = tid & 15;
    float sr[16], si[16];
    #pragma unroll
    for (int a = 0; a < 16; ++a){
      uint_t u = Z[j1*ZJS + a*16 + b1c];
      sr[a] = bf_lo(u); si[a] = bf_hi(u);
    }
    fft16_inv(sr, si);
    float2 ws = ph[b1c];
    float wr = 1.f/256.f, wi = 0.f;    // folds the 1/256 v-normalization
    #pragma unroll
    for (int d = 0; d < 16; ++d){
      float yr = sr[BR16T[d]], yi = si[BR16T[d]];
      Z[j1*ZJS + d*16 + b1c] = packf2(yr*wr - yi*wi, yr*wi + yi*wr);
      float nw = wr*ws.x - wi*ws.y;
      wi = wr*ws.y + wi*ws.x; wr = nw;
    }
  }
  __syncthreads();

  // ---------- v-IFFT stage 2: FFT16 over b, store packed planes ----------
  {
    const int j2 = tid >> 4;
    const int d2 = tid & 15;
    float br[16], bi[16];
    const uint4* zb = (const uint4*)&Z[j2*ZJS + d2*16];
    #pragma unroll
    for (int c = 0; c < 4; ++c){
      uint4 u4 = zb[c];
      br[c*4+0] = bf_lo(u4.x); bi[c*4+0] = bf_hi(u4.x);
      br[c*4+1] = bf_lo(u4.y); bi[c*4+1] = bf_hi(u4.y);
      br[c*4+2] = bf_lo(u4.z); bi[c*4+2] = bf_hi(u4.z);
      br[c*4+3] = bf_lo(u4.w); bi[c*4+3] = bf_hi(u4.w);
    }
    fft16_inv(br, bi);
    const long rowbase = (long)(cr0 + j2) * 256;
    #pragma unroll
    for (int p = 0; p < 16; ++p)
      OutP[rowbase + BR16T[p]*16 + d2] = packf2(br[p], bi[p]);
  }
  #undef STAGE_B
  #undef STAGE_A
}

// ---------------- m-axis IFFT: 16x16 four-step, in-place on packed planes ----------------
__global__ __launch_bounds__(256)
void fft_m(uint_t* __restrict__ P, const float2* __restrict__ ph){
  __shared__ uint_t Z[4352];           // [d][b][v], strides d=272, b=17, v=1
  const int tid = threadIdx.x;
  const int v = tid & 15;
  const int b = tid >> 4;
  const int bB = blockIdx.x >> 4;
  const int vg = (blockIdx.x & 15) << 4;
  const long base = (long)bB*65536 + vg + v;

  float xr[16], xi[16];
  #pragma unroll
  for (int a = 0; a < 16; ++a){
    uint_t u = P[base + (long)(a*16 + b)*256];
    xr[a] = bf_lo(u); xi[a] = bf_hi(u);
  }
  fft16_inv(xr, xi);
  float2 ws = ph[b];
  float wr = 1.f/256.f, wi = 0.f;      // folds 1/256
  #pragma unroll
  for (int d = 0; d < 16; ++d){
    float yr = xr[BR16T[d]], yi = xi[BR16T[d]];
    Z[d*272 + b*17 + v] = packf2(yr*wr - yi*wi, yr*wi + yi*wr);
    float nw = wr*ws.x - wi*ws.y; wi = wr*ws.y + wi*ws.x; wr = nw;
  }
  __syncthreads();
  const int d2 = tid >> 4;
  float br[16], bi[16];
  #pragma unroll
  for (int bb = 0; bb < 16; ++bb){
    uint_t u = Z[d2*272 + bb*17 + v];
    br[bb] = bf_lo(u); bi[bb] = bf_hi(u);
  }
  fft16_inv(br, bi);
  #pragma unroll
  for (int p = 0; p < 16; ++p)
    P[base + (long)(BR16T[p]*16 + d2)*256] = packf2(br[p], bi[p]);
}

// ---------------- b-axis IFFT: 32x16 four-step, in-place, REAL fp32 out ----------------
__global__ __launch_bounds__(256)
void fft_b(uint_t* __restrict__ P, const float2* __restrict__ t512){
  __shared__ uint_t Z[8704];           // [d][b][v], strides d=272, b=17, v=1
  const int tid = threadIdx.x;
  const int v = tid & 15;
  const int b = tid >> 4;
  const int m = blockIdx.x >> 4;
  const int vg = (blockIdx.x & 15) << 4;
  const long base = (long)m*256 + vg + v;

  float xr[32], xi[32];
  #pragma unroll
  for (int a = 0; a < 32; ++a){
    uint_t u = P[base + (long)(a*16 + b)*65536];
    xr[a] = bf_lo(u); xi[a] = bf_hi(u);
  }
  fft32_inv(xr, xi);
  float2 ws = t512[b];
  float wr = 1.f/512.f, wi = 0.f;      // folds 1/512
  #pragma unroll
  for (int d = 0; d < 32; ++d){
    float yr = xr[BR32T[d]], yi = xi[BR32T[d]];
    Z[d*272 + b*17 + v] = packf2(yr*wr - yi*wi, yr*wi + yi*wr);
    float nw = wr*ws.x - wi*ws.y; wi = wr*ws.y + wi*ws.x; wr = nw;
  }
  __syncthreads();
  float* out = (float*)P;
  #pragma unroll
  for (int h = 0; h < 2; ++h){
    const int d = (tid >> 4) + 16*h;
    float br[16], bi[16];
    #pragma unroll
    for (int bb = 0; bb < 16; ++bb){
      uint_t u = Z[d*272 + bb*17 + v];
      br[bb] = bf_lo(u); bi[bb] = bf_hi(u);
    }
    fft16_inv(br, bi);
    #pragma unroll
    for (int p = 0; p < 16; ++p)
      out[base + (long)(BR16T[p]*32 + d)*65536] = br[p];
  }
}

// ---------------- launch ----------------
extern "C" void kernel_launch(void* const* d_in, const int* in_sizes, int n_in,
                              void* d_out, int out_size, void* d_ws, size_t ws_size,
                              hipStream_t stream) {
  (void)in_sizes; (void)n_in; (void)out_size; (void)ws_size;
  const float* x      = (const float*)d_in[0];
  const float* w0     = (const float*)d_in[1];
  const float* w1     = (const float*)d_in[2];
  const float* lin1_w = (const float*)d_in[3];
  const float* lin1_b = (const float*)d_in[4];
  const float* lin2_w = (const float*)d_in[5];
  const float* lin2_b = (const float*)d_in[6];

  // ws smalls only (~2.5 MB)
  char* sm = (char*)d_ws;
  float2*   Yw     = (float2*)sm;   sm += 1048576;
  float*    Xr     = (float*)sm;    sm += 524288;
  float*    Xi     = (float*)sm;    sm += 524288;
  float2*   t256f  = (float2*)sm;   sm += 2048;
  float2*   t256i  = (float2*)sm;   sm += 2048;
  float2*   t512f  = (float2*)sm;   sm += 4096;
  float2*   t512i  = (float2*)sm;   sm += 4096;
  ushort_t* Wct    = (ushort_t*)sm; sm += 131072;
  ushort_t* W2b    = (ushort_t*)sm; sm += 131072;

  uint_t* planes = (uint_t*)d_out;    // packed bf16 complex planes, 134 MB

  fill_tables<<<1, 512, 0, stream>>>(t256f, t256i, t512f, t512i);
  dft_m<<<512, 256, 0, stream>>>(x, Yw, t256f);
  dft_b<<<512, 256, 0, stream>>>(Yw, Xr, Xi, t512f);
  prep_w<<<256, 256, 0, stream>>>(w1, lin1_w, lin2_w, Wct, W2b);
  fused_mid<<<4096, 512, 0, stream>>>(Xr, Xi, w0, Wct, W2b, lin1_b, lin2_b,
                                      t256i, planes);
  fft_m<<<8192, 256, 0, stream>>>(planes, t256i);
  fft_b<<<4096, 256, 0, stream>>>(planes, t512i);
}